// Round 1
// baseline (334.432 us; speedup 1.0000x reference)
//
#include <hip/hip_runtime.h>
#include <stdint.h>

// Problem constants (B=4 fixed by setup_inputs)
#define BATCH 4
#define NC 2000            // curves per batch
#define NS 4000            // surfaces per batch
#define NL 2000            // line samples per batch
#define NT 26000           // triangle samples per batch
#define NF 8000            // faces per batch
#define NX (NC + NL + NS + NT)      // 34000 points per batch
#define X_SIZE (BATCH * NX * 3)     // 408000 floats
#define OD 258                      // occ spatial dim (256 + 2*2 - 3 + 1)
#define MASK_WPB (256 * 256 * 8)    // mask words per batch (256^3 bits)
#define MASK_WORDS (BATCH * MASK_WPB)

// Kernel 1: compute all 34000*B sample points, write x, and set voxel bits.
// All float math via _rn intrinsics in numpy evaluation order (no fma
// contraction) so the int-cast voxel coords bit-match the reference.
__global__ void points_kernel(const float* __restrict__ curves,
                              const float* __restrict__ surfaces,
                              const float* __restrict__ t_line,
                              const float* __restrict__ uv,
                              const int* __restrict__ lines_array,
                              const int* __restrict__ faces_array,
                              const int* __restrict__ line_choice,
                              const int* __restrict__ tri_choice,
                              float* __restrict__ x_out,
                              uint32_t* __restrict__ mask) {
    int t = blockIdx.x * blockDim.x + threadIdx.x;
    if (t >= BATCH * NX) return;
    int b = t / NX;
    int n = t - b * NX;

    float px, py, pz;
    if (n < NC) {
        const float* p = curves + (size_t)(b * NC + n) * 3;
        px = p[0]; py = p[1]; pz = p[2];
    } else if (n < NC + NL) {
        int i = n - NC;
        int lc = line_choice[b * NL + i];
        int l0 = lines_array[(size_t)(b * NL + lc) * 2 + 0];
        int l1 = lines_array[(size_t)(b * NL + lc) * 2 + 1];
        const float* pa = curves + (size_t)(b * NC + l0) * 3;
        const float* pb = curves + (size_t)(b * NC + l1) * 3;
        float tt = t_line[b * NL + i];
        px = __fadd_rn(pa[0], __fmul_rn(tt, __fsub_rn(pb[0], pa[0])));
        py = __fadd_rn(pa[1], __fmul_rn(tt, __fsub_rn(pb[1], pa[1])));
        pz = __fadd_rn(pa[2], __fmul_rn(tt, __fsub_rn(pb[2], pa[2])));
    } else if (n < NC + NL + NS) {
        int i = n - (NC + NL);
        const float* p = surfaces + (size_t)(b * NS + i) * 3;
        px = p[0]; py = p[1]; pz = p[2];
    } else {
        int i = n - (NC + NL + NS);
        int tc = tri_choice[b * NT + i];
        int f0 = faces_array[(size_t)(b * NF + tc) * 3 + 0];
        int f1 = faces_array[(size_t)(b * NF + tc) * 3 + 1];
        int f2 = faces_array[(size_t)(b * NF + tc) * 3 + 2];
        const float* ta = surfaces + (size_t)(b * NS + f0) * 3;
        const float* tb = surfaces + (size_t)(b * NS + f1) * 3;
        const float* tcv = surfaces + (size_t)(b * NS + f2) * 3;
        float u = uv[(size_t)(b * NT + i) * 2 + 0];
        float v = uv[(size_t)(b * NT + i) * 2 + 1];
        if (__fadd_rn(u, v) > 1.0f) {
            u = __fsub_rn(1.0f, u);
            v = __fsub_rn(1.0f, v);
        }
        px = __fadd_rn(__fadd_rn(ta[0], __fmul_rn(u, __fsub_rn(tb[0], ta[0]))),
                       __fmul_rn(v, __fsub_rn(tcv[0], ta[0])));
        py = __fadd_rn(__fadd_rn(ta[1], __fmul_rn(u, __fsub_rn(tb[1], ta[1]))),
                       __fmul_rn(v, __fsub_rn(tcv[1], ta[1])));
        pz = __fadd_rn(__fadd_rn(ta[2], __fmul_rn(u, __fsub_rn(tb[2], ta[2]))),
                       __fmul_rn(v, __fsub_rn(tcv[2], ta[2])));
    }

    float* xo = x_out + (size_t)t * 3;
    xo[0] = px; xo[1] = py; xo[2] = pz;

    // cube = int(clip(x*256 + 128.5, 0, 255)) — truncation == floor here
    float cx = fminf(fmaxf(__fadd_rn(__fmul_rn(px, 256.0f), 128.5f), 0.0f), 255.0f);
    float cy = fminf(fmaxf(__fadd_rn(__fmul_rn(py, 256.0f), 128.5f), 0.0f), 255.0f);
    float cz = fminf(fmaxf(__fadd_rn(__fmul_rn(pz, 256.0f), 128.5f), 0.0f), 255.0f);
    int ix = (int)cx, iy = (int)cy, iz = (int)cz;

    atomicOr(&mask[(((size_t)b * 256 + ix) * 256 + iy) * 8 + (iz >> 5)],
             1u << (iz & 31));
}

// Kernel 2: one block per (b, output-i). OR the i-window rows into LDS,
// OR across j-window + smear along k, then stream coalesced float stores.
__global__ void __launch_bounds__(256) occ_kernel(const uint32_t* __restrict__ mask,
                                                  float* __restrict__ occ) {
    int blk = blockIdx.x;           // b*OD + i
    int b = blk / OD;
    int i = blk - b * OD;

    __shared__ uint32_t rowOR[256][8];   // OR over i-window, per (j, word)
    __shared__ uint32_t smear[OD][9];    // per output j, smeared k-words

    int i0 = max(i - 2, 0), i1 = min(i, 255);
    const uint32_t* mb = mask + (size_t)b * MASK_WPB;

    // Phase 1: rowOR[jj][w] = OR over ii in [i-2, i] of mask rows
    for (int idx = threadIdx.x; idx < 256 * 8; idx += 256) {
        int jj = idx >> 3, w = idx & 7;
        uint32_t v = 0;
        for (int ii = i0; ii <= i1; ++ii)
            v |= mb[((size_t)ii * 256 + jj) * 8 + w];
        rowOR[jj][w] = v;
    }
    __syncthreads();

    // Phase 2: OR across j-window, then smear bits k-2..k into each bit k.
    // Word 8 holds k=256..257 (carry-out of word 7).
    for (int idx = threadIdx.x; idx < OD * 9; idx += 256) {
        int j = idx / 9, w = idx - j * 9;
        int j0 = max(j - 2, 0), j1 = min(j, 255);
        uint32_t c = 0, cp = 0;
        for (int jj = j0; jj <= j1; ++jj) {
            if (w < 8) c |= rowOR[jj][w];
            if (w > 0) cp |= rowOR[jj][w - 1];
        }
        smear[j][w] = c | (c << 1) | (c << 2) | (cp >> 31) | (cp >> 30);
    }
    __syncthreads();

    // Phase 3: coalesced write-out of 258*258 floats for this (b,i) slab.
    float* out = occ + (size_t)blk * (OD * OD);
    for (int idx = threadIdx.x; idx < OD * OD; idx += 256) {
        int j = idx / OD, k = idx - j * OD;
        uint32_t bit = (smear[j][k >> 5] >> (k & 31)) & 1u;
        out[idx] = (float)bit;
    }
}

extern "C" void kernel_launch(void* const* d_in, const int* in_sizes, int n_in,
                              void* d_out, int out_size, void* d_ws, size_t ws_size,
                              hipStream_t stream) {
    // setup_inputs order:
    // 0 imgs (unused), 1 curves, 2 surfaces, 3 t_line, 4 uv,
    // 5 lines_array, 6 faces_array, 7 indices_array (unused),
    // 8 line_choice, 9 tri_choice
    const float* curves      = (const float*)d_in[1];
    const float* surfaces    = (const float*)d_in[2];
    const float* t_line      = (const float*)d_in[3];
    const float* uv          = (const float*)d_in[4];
    const int*   lines_array = (const int*)d_in[5];
    const int*   faces_array = (const int*)d_in[6];
    const int*   line_choice = (const int*)d_in[8];
    const int*   tri_choice  = (const int*)d_in[9];

    float* out = (float*)d_out;
    uint32_t* mask = (uint32_t*)d_ws;   // 8 MB bitmask scratch

    // d_ws is re-poisoned to 0xAA before every launch — zero the mask.
    hipMemsetAsync(mask, 0, (size_t)MASK_WORDS * sizeof(uint32_t), stream);

    int npts = BATCH * NX;
    points_kernel<<<(npts + 255) / 256, 256, 0, stream>>>(
        curves, surfaces, t_line, uv, lines_array, faces_array,
        line_choice, tri_choice, out, mask);

    occ_kernel<<<BATCH * OD, 256, 0, stream>>>(mask, out + X_SIZE);
}

// Round 2
// 323.342 us; speedup vs baseline: 1.0343x; 1.0343x over previous
//
#include <hip/hip_runtime.h>
#include <stdint.h>

// Problem constants (B=4 fixed by setup_inputs)
#define BATCH 4
#define NC 2000            // curves per batch
#define NS 4000            // surfaces per batch
#define NL 2000            // line samples per batch
#define NT 26000           // triangle samples per batch
#define NF 8000            // faces per batch
#define NX (NC + NL + NS + NT)      // 34000 points per batch
#define X_SIZE (BATCH * NX * 3)     // 408000 floats (16B-aligned: 1632000 B)
#define OD 258                      // occ spatial dim (256 + 2*2 - 3 + 1)
#define MASK_WPB (256 * 256 * 8)    // mask words per batch (256^3 bits)
#define MASK_WORDS (BATCH * MASK_WPB)

// Kernel 1: compute all 34000*B sample points, write x, and set voxel bits.
// All float math via _rn intrinsics in numpy evaluation order (no fma
// contraction) so the int-cast voxel coords bit-match the reference.
// (absmax 2e-3 at R1 — do not touch the arithmetic.)
__global__ void points_kernel(const float* __restrict__ curves,
                              const float* __restrict__ surfaces,
                              const float* __restrict__ t_line,
                              const float* __restrict__ uv,
                              const int* __restrict__ lines_array,
                              const int* __restrict__ faces_array,
                              const int* __restrict__ line_choice,
                              const int* __restrict__ tri_choice,
                              float* __restrict__ x_out,
                              uint32_t* __restrict__ mask) {
    int t = blockIdx.x * blockDim.x + threadIdx.x;
    if (t >= BATCH * NX) return;
    int b = t / NX;
    int n = t - b * NX;

    float px, py, pz;
    if (n < NC) {
        const float* p = curves + (size_t)(b * NC + n) * 3;
        px = p[0]; py = p[1]; pz = p[2];
    } else if (n < NC + NL) {
        int i = n - NC;
        int lc = line_choice[b * NL + i];
        int l0 = lines_array[(size_t)(b * NL + lc) * 2 + 0];
        int l1 = lines_array[(size_t)(b * NL + lc) * 2 + 1];
        const float* pa = curves + (size_t)(b * NC + l0) * 3;
        const float* pb = curves + (size_t)(b * NC + l1) * 3;
        float tt = t_line[b * NL + i];
        px = __fadd_rn(pa[0], __fmul_rn(tt, __fsub_rn(pb[0], pa[0])));
        py = __fadd_rn(pa[1], __fmul_rn(tt, __fsub_rn(pb[1], pa[1])));
        pz = __fadd_rn(pa[2], __fmul_rn(tt, __fsub_rn(pb[2], pa[2])));
    } else if (n < NC + NL + NS) {
        int i = n - (NC + NL);
        const float* p = surfaces + (size_t)(b * NS + i) * 3;
        px = p[0]; py = p[1]; pz = p[2];
    } else {
        int i = n - (NC + NL + NS);
        int tc = tri_choice[b * NT + i];
        int f0 = faces_array[(size_t)(b * NF + tc) * 3 + 0];
        int f1 = faces_array[(size_t)(b * NF + tc) * 3 + 1];
        int f2 = faces_array[(size_t)(b * NF + tc) * 3 + 2];
        const float* ta = surfaces + (size_t)(b * NS + f0) * 3;
        const float* tb = surfaces + (size_t)(b * NS + f1) * 3;
        const float* tcv = surfaces + (size_t)(b * NS + f2) * 3;
        float u = uv[(size_t)(b * NT + i) * 2 + 0];
        float v = uv[(size_t)(b * NT + i) * 2 + 1];
        if (__fadd_rn(u, v) > 1.0f) {
            u = __fsub_rn(1.0f, u);
            v = __fsub_rn(1.0f, v);
        }
        px = __fadd_rn(__fadd_rn(ta[0], __fmul_rn(u, __fsub_rn(tb[0], ta[0]))),
                       __fmul_rn(v, __fsub_rn(tcv[0], ta[0])));
        py = __fadd_rn(__fadd_rn(ta[1], __fmul_rn(u, __fsub_rn(tb[1], ta[1]))),
                       __fmul_rn(v, __fsub_rn(tcv[1], ta[1])));
        pz = __fadd_rn(__fadd_rn(ta[2], __fmul_rn(u, __fsub_rn(tb[2], ta[2]))),
                       __fmul_rn(v, __fsub_rn(tcv[2], ta[2])));
    }

    float* xo = x_out + (size_t)t * 3;
    xo[0] = px; xo[1] = py; xo[2] = pz;

    // cube = int(clip(x*256 + 128.5, 0, 255)) — truncation == floor here
    float cx = fminf(fmaxf(__fadd_rn(__fmul_rn(px, 256.0f), 128.5f), 0.0f), 255.0f);
    float cy = fminf(fmaxf(__fadd_rn(__fmul_rn(py, 256.0f), 128.5f), 0.0f), 255.0f);
    float cz = fminf(fmaxf(__fadd_rn(__fmul_rn(pz, 256.0f), 128.5f), 0.0f), 255.0f);
    int ix = (int)cx, iy = (int)cy, iz = (int)cz;

    atomicOr(&mask[(((size_t)b * 256 + ix) * 256 + iy) * 8 + (iz >> 5)],
             1u << (iz & 31));
}

// Kernel 2: one block per (b, output-i). OR the i-window rows into LDS
// (uint4 global loads), OR across j-window + smear along k, then stream
// float4 coalesced stores (store-BW-bound: 275 MB total output).
__global__ void __launch_bounds__(256) occ_kernel(const uint32_t* __restrict__ mask,
                                                  float* __restrict__ occ) {
    int blk = blockIdx.x;           // b*OD + i
    int b = blk / OD;
    int i = blk - b * OD;

    __shared__ uint32_t rowOR[256][8];   // OR over i-window, per (j, word)
    __shared__ uint32_t smear[OD][9];    // per output j, smeared k-words

    int i0 = max(i - 2, 0), i1 = min(i, 255);
    const uint4* mb4 = (const uint4*)(mask + (size_t)b * MASK_WPB);

    // Phase 1: rowOR[jj][*] = OR over ii in [i-2, i], as 2 uint4 per row.
    // 256 rows x 2 uint4 = 512 items / 256 threads = 2 iters.
    for (int idx = threadIdx.x; idx < 256 * 2; idx += 256) {
        int jj = idx >> 1, h = idx & 1;
        uint4 v = mb4[((size_t)i0 * 256 + jj) * 2 + h];
        for (int ii = i0 + 1; ii <= i1; ++ii) {
            uint4 w = mb4[((size_t)ii * 256 + jj) * 2 + h];
            v.x |= w.x; v.y |= w.y; v.z |= w.z; v.w |= w.w;
        }
        *(uint4*)&rowOR[jj][h * 4] = v;   // 32B row stride -> 16B aligned
    }
    __syncthreads();

    // Phase 2: OR across j-window, then smear bits k-2..k into each bit k.
    // Word 8 holds k=256..257 (carry-out of word 7).
    for (int idx = threadIdx.x; idx < OD * 9; idx += 256) {
        int j = idx / 9, w = idx - j * 9;
        int j0 = max(j - 2, 0), j1 = min(j, 255);
        uint32_t c = 0, cp = 0;
        for (int jj = j0; jj <= j1; ++jj) {
            if (w < 8) c |= rowOR[jj][w];
            if (w > 0) cp |= rowOR[jj][w - 1];
        }
        smear[j][w] = c | (c << 1) | (c << 2) | (cp >> 31) | (cp >> 30);
    }
    __syncthreads();

    // Phase 3: float4 write-out of 258*258 floats for this (b,i) slab.
    // Slab base: X_SIZE*4 B and 66564*4 B per slab are both 16B-multiples.
    float4* out4 = (float4*)(occ + (size_t)blk * (OD * OD));
    const int NQ = (OD * OD) / 4;   // 16641
    for (int q = threadIdx.x; q < NQ; q += 256) {
        int f = q * 4;
        int j = f / OD, k = f - j * OD;
        float r[4];
        #pragma unroll
        for (int e = 0; e < 4; ++e) {
            uint32_t bit = (smear[j][k >> 5] >> (k & 31)) & 1u;
            r[e] = (float)bit;
            if (++k == OD) { k = 0; ++j; }
        }
        out4[q] = make_float4(r[0], r[1], r[2], r[3]);
    }
}

extern "C" void kernel_launch(void* const* d_in, const int* in_sizes, int n_in,
                              void* d_out, int out_size, void* d_ws, size_t ws_size,
                              hipStream_t stream) {
    // setup_inputs order:
    // 0 imgs (unused), 1 curves, 2 surfaces, 3 t_line, 4 uv,
    // 5 lines_array, 6 faces_array, 7 indices_array (unused),
    // 8 line_choice, 9 tri_choice
    const float* curves      = (const float*)d_in[1];
    const float* surfaces    = (const float*)d_in[2];
    const float* t_line      = (const float*)d_in[3];
    const float* uv          = (const float*)d_in[4];
    const int*   lines_array = (const int*)d_in[5];
    const int*   faces_array = (const int*)d_in[6];
    const int*   line_choice = (const int*)d_in[8];
    const int*   tri_choice  = (const int*)d_in[9];

    float* out = (float*)d_out;
    uint32_t* mask = (uint32_t*)d_ws;   // 8 MB bitmask scratch

    // d_ws is re-poisoned to 0xAA before every launch — zero the mask.
    hipMemsetAsync(mask, 0, (size_t)MASK_WORDS * sizeof(uint32_t), stream);

    int npts = BATCH * NX;
    points_kernel<<<(npts + 255) / 256, 256, 0, stream>>>(
        curves, surfaces, t_line, uv, lines_array, faces_array,
        line_choice, tri_choice, out, mask);

    occ_kernel<<<BATCH * OD, 256, 0, stream>>>(mask, out + X_SIZE);
}